// Round 4
// baseline (103.805 us; speedup 1.0000x reference)
//
#include <hip/hip_runtime.h>
#include <hip/hip_bf16.h>
#include <math.h>

#define N_NODES 8192
#define DIM 256
#define WPR 256      // LDS dedup bitmap words per row = 8192/32
#define LSTRIDE 128  // per-row list stride (ushort); raw degree ~Binom(262144,1/8192), mean 32, P(>128)~0

typedef __attribute__((ext_vector_type(8))) short bf16x8;
typedef __attribute__((ext_vector_type(4))) float f32x4;

// ================= p0: zero lens cursors + convert W to bf16 (one tiny kernel) =================
// threads [0,2048): zero 8192 ints of lens (uint4 each)
// threads [2048,10240): convert 8 W floats each (65536 elems)
__global__ __launch_bounds__(256) void p0_prep(const float* __restrict__ W,
                                               __hip_bfloat16* __restrict__ Wb,
                                               int* __restrict__ lens) {
    int t = blockIdx.x * 256 + threadIdx.x;
    if (t < N_NODES / 4) {
        uint4 z = {0u, 0u, 0u, 0u};
        ((uint4*)lens)[t] = z;
    }
    int w = t - N_NODES / 4;
    if (w >= 0 && w < DIM * DIM / 8) {
        size_t off = (size_t)w * 8;
        float4 v0 = *(const float4*)(W + off);
        float4 v1 = *(const float4*)(W + off + 4);
        union { __hip_bfloat16 h[8]; uint4 u; } c;
        c.h[0] = __float2bfloat16(v0.x); c.h[1] = __float2bfloat16(v0.y);
        c.h[2] = __float2bfloat16(v0.z); c.h[3] = __float2bfloat16(v0.w);
        c.h[4] = __float2bfloat16(v1.x); c.h[5] = __float2bfloat16(v1.y);
        c.h[6] = __float2bfloat16(v1.z); c.h[7] = __float2bfloat16(v1.w);
        *(uint4*)(Wb + off) = c.u;
    }
}

// ================= k1: edge scatter (append col to row's raw list via cursor) =================
__global__ __launch_bounds__(256) void k1_scatter(const int* __restrict__ ei,
                                                  unsigned short* __restrict__ list,
                                                  int* __restrict__ lens, int E) {
    int sid = blockIdx.x * 256 + threadIdx.x;
    int snth = gridDim.x * 256;
    const int* rows = ei;
    const int* cols = ei + E;
    for (int e = sid; e < E; e += snth) {
        int r = rows[e];
        int c = cols[e];
        int pos = atomicAdd(&lens[r], 1);
        if (pos < LSTRIDE) list[(size_t)r * LSTRIDE + pos] = (unsigned short)c;
    }
}

// ================= k2: MFMA gemm (blocks [0,512)) || wave-local dedup+dinv (blocks [512,1024)) ==
// gemm: g = bf16(x @ W^T) UNSCALED, x read as fp32 and converted to bf16 in-register.
// dedup: one wave per row; 1KB LDS bitmap; atomicOr-returns-old gives exactly-one-keep;
//        ballot prefix-sum compacts kept cols in place; append self-loop if absent.
__global__ __launch_bounds__(256) void k2_gemm_dedup(
        const float* __restrict__ x, const short* __restrict__ Wb, __hip_bfloat16* __restrict__ g,
        unsigned short* __restrict__ list, int* __restrict__ lens, float* __restrict__ dinv) {
    __shared__ unsigned sbm[4][WPR];  // 4 KB; wave-private regions, no __syncthreads needed
    if ((int)blockIdx.x < 512) {
        int tid = threadIdx.x;
        int wave = tid >> 6, lane = tid & 63;
        int quad = lane >> 4, l16 = lane & 15;
        int t = blockIdx.x;
        int bm = (t & 127) * 64 + wave * 16;
        int bn = (t >> 7) * 64;
        f32x4 acc[4] = {};
        const float* arow = x + (size_t)(bm + l16) * DIM + quad * 8;
#pragma unroll
        for (int k0 = 0; k0 < DIM; k0 += 32) {
            float4 v0 = *(const float4*)(arow + k0);
            float4 v1 = *(const float4*)(arow + k0 + 4);
            union { __hip_bfloat16 h[8]; bf16x8 v; } ac;
            ac.h[0] = __float2bfloat16(v0.x); ac.h[1] = __float2bfloat16(v0.y);
            ac.h[2] = __float2bfloat16(v0.z); ac.h[3] = __float2bfloat16(v0.w);
            ac.h[4] = __float2bfloat16(v1.x); ac.h[5] = __float2bfloat16(v1.y);
            ac.h[6] = __float2bfloat16(v1.z); ac.h[7] = __float2bfloat16(v1.w);
#pragma unroll
            for (int s = 0; s < 4; s++) {
                bf16x8 b = *(const bf16x8*)(Wb + (size_t)(bn + s * 16 + l16) * DIM + k0 + quad * 8);
                acc[s] = __builtin_amdgcn_mfma_f32_16x16x32_bf16(ac.v, b, acc[s], 0, 0, 0);
            }
        }
        // C/D layout: col = lane&15 (n), row = quad*4 + r (m)
#pragma unroll
        for (int r = 0; r < 4; r++) {
            int m = bm + quad * 4 + r;
#pragma unroll
            for (int s = 0; s < 4; s++)
                g[(size_t)m * DIM + bn + s * 16 + l16] = __float2bfloat16(acc[s][r]);
        }
    } else {
        int bid = blockIdx.x - 512;
        int wave = threadIdx.x >> 6, lane = threadIdx.x & 63;
        for (int row = bid * 4 + wave; row < N_NODES; row += 512 * 4) {
            uint4 z = {0u, 0u, 0u, 0u};
            *(uint4*)&sbm[wave][lane * 4] = z;
            unsigned short* lp = list + (size_t)row * LSTRIDE;
            int raw = lens[row];
            if (raw > LSTRIDE) raw = LSTRIDE;
            // load both halves BEFORE any store (wave-wide vmcnt orders load->use->store)
            int c0 = (lane < raw) ? (int)lp[lane] : -1;
            int c1 = (64 + lane < raw) ? (int)lp[64 + lane] : -1;
            int new0 = 0, new1 = 0;
            if (c0 >= 0) {
                unsigned old = atomicOr(&sbm[wave][c0 >> 5], 1u << (c0 & 31));
                new0 = !((old >> (c0 & 31)) & 1u);
            }
            if (c1 >= 0) {
                unsigned old = atomicOr(&sbm[wave][c1 >> 5], 1u << (c1 & 31));
                new1 = !((old >> (c1 & 31)) & 1u);
            }
            unsigned long long m0 = __ballot(new0);
            unsigned long long m1 = __ballot(new1);
            unsigned long long below = (1ull << lane) - 1ull;  // lane 63: 0x7fff... correct
            int kept0 = __popcll(m0);
            int pos0 = __popcll(m0 & below);
            int pos1 = kept0 + __popcll(m1 & below);
            int total = kept0 + __popcll(m1);
            int diag = (int)((sbm[wave][row >> 5] >> (row & 31)) & 1u);  // LDS in-order per wave
            if (new0) lp[pos0] = (unsigned short)c0;
            if (new1) lp[pos1] = (unsigned short)c1;
            if (!diag && lane == 0) lp[total] = (unsigned short)row;
            if (lane == 0) {
                int len = total + (diag ? 0 : 1);
                lens[row] = len;
                dinv[row] = 1.0f / sqrtf((float)len + 1e-5f);
            }
        }
    }
}

// ================= k3: out[i] = relu(dinv_i * sum_j dinv_j * g[j]) =================
// one row per 128-thread block; 4 neighbor-groups x 32 lanes; 16B gathers; LDS cross-group reduce.
// staging loads guarded by tid < len (only ~33 of 128 slots are live).
__global__ __launch_bounds__(128) void k3_aggregate(
        const unsigned short* __restrict__ list, const int* __restrict__ lens,
        const float* __restrict__ dinv, const uint4* __restrict__ g4, float* __restrict__ out) {
    __shared__ unsigned short snbr[LSTRIDE];
    __shared__ float sdj[LSTRIDE];
    __shared__ float part[4][DIM];
    int row = blockIdx.x;
    int tid = threadIdx.x;
    int len = lens[row];  // block-uniform -> scalar load
    if (tid < len) {
        unsigned short nb = list[(size_t)row * LSTRIDE + tid];
        snbr[tid] = nb;
        sdj[tid] = dinv[nb];
    }
    __syncthreads();
    int gq = tid >> 5, l = tid & 31;
    float a0 = 0.f, a1 = 0.f, a2 = 0.f, a3 = 0.f, a4 = 0.f, a5 = 0.f, a6 = 0.f, a7 = 0.f;
    float b0 = 0.f, b1 = 0.f, b2 = 0.f, b3 = 0.f, b4 = 0.f, b5 = 0.f, b6 = 0.f, b7 = 0.f;
    int i = gq;
    for (; i + 4 < len; i += 8) {
        int n0 = snbr[i];
        int n1 = snbr[i + 4];
        float d0 = sdj[i];
        float d1 = sdj[i + 4];
        uint4 u0 = g4[(size_t)n0 * 32 + l];
        uint4 u1 = g4[(size_t)n1 * 32 + l];
        a0 = fmaf(d0, __uint_as_float(u0.x << 16), a0);
        a1 = fmaf(d0, __uint_as_float(u0.x & 0xffff0000u), a1);
        a2 = fmaf(d0, __uint_as_float(u0.y << 16), a2);
        a3 = fmaf(d0, __uint_as_float(u0.y & 0xffff0000u), a3);
        a4 = fmaf(d0, __uint_as_float(u0.z << 16), a4);
        a5 = fmaf(d0, __uint_as_float(u0.z & 0xffff0000u), a5);
        a6 = fmaf(d0, __uint_as_float(u0.w << 16), a6);
        a7 = fmaf(d0, __uint_as_float(u0.w & 0xffff0000u), a7);
        b0 = fmaf(d1, __uint_as_float(u1.x << 16), b0);
        b1 = fmaf(d1, __uint_as_float(u1.x & 0xffff0000u), b1);
        b2 = fmaf(d1, __uint_as_float(u1.y << 16), b2);
        b3 = fmaf(d1, __uint_as_float(u1.y & 0xffff0000u), b3);
        b4 = fmaf(d1, __uint_as_float(u1.z << 16), b4);
        b5 = fmaf(d1, __uint_as_float(u1.z & 0xffff0000u), b5);
        b6 = fmaf(d1, __uint_as_float(u1.w << 16), b6);
        b7 = fmaf(d1, __uint_as_float(u1.w & 0xffff0000u), b7);
    }
    if (i < len) {
        int n0 = snbr[i];
        float d0 = sdj[i];
        uint4 u0 = g4[(size_t)n0 * 32 + l];
        a0 = fmaf(d0, __uint_as_float(u0.x << 16), a0);
        a1 = fmaf(d0, __uint_as_float(u0.x & 0xffff0000u), a1);
        a2 = fmaf(d0, __uint_as_float(u0.y << 16), a2);
        a3 = fmaf(d0, __uint_as_float(u0.y & 0xffff0000u), a3);
        a4 = fmaf(d0, __uint_as_float(u0.z << 16), a4);
        a5 = fmaf(d0, __uint_as_float(u0.z & 0xffff0000u), a5);
        a6 = fmaf(d0, __uint_as_float(u0.w << 16), a6);
        a7 = fmaf(d0, __uint_as_float(u0.w & 0xffff0000u), a7);
    }
    float* pp = &part[gq][l * 8];
    pp[0] = a0 + b0; pp[1] = a1 + b1; pp[2] = a2 + b2; pp[3] = a3 + b3;
    pp[4] = a4 + b4; pp[5] = a5 + b5; pp[6] = a6 + b6; pp[7] = a7 + b7;
    __syncthreads();
    int f0 = tid * 2;
    float s = dinv[row];
    float r0 = (part[0][f0] + part[1][f0]) + (part[2][f0] + part[3][f0]);
    float r1 = (part[0][f0 + 1] + part[1][f0 + 1]) + (part[2][f0 + 1] + part[3][f0 + 1]);
    float2 o;
    o.x = fmaxf(s * r0, 0.f);
    o.y = fmaxf(s * r1, 0.f);
    *(float2*)(out + (size_t)row * DIM + f0) = o;
}

extern "C" void kernel_launch(void* const* d_in, const int* in_sizes, int n_in,
                              void* d_out, int out_size, void* d_ws, size_t ws_size,
                              hipStream_t stream) {
    const float* x = (const float*)d_in[0];
    const int* ei = (const int*)d_in[1];   // [2, E] flat: rows then cols
    const float* W = (const float*)d_in[2];
    float* out = (float*)d_out;
    int E = in_sizes[1] / 2;

    unsigned char* ws = (unsigned char*)d_ws;
    size_t off = 0;
    int* lens = (int*)(ws + off);                       off += (size_t)N_NODES * 4;            // 32 KB
    float* dinv = (float*)(ws + off);                   off += (size_t)N_NODES * 4;            // 32 KB
    unsigned short* list = (unsigned short*)(ws + off); off += (size_t)N_NODES * LSTRIDE * 2;  // 2 MB
    __hip_bfloat16* Wb = (__hip_bfloat16*)(ws + off);   off += (size_t)DIM * DIM * 2;          // 128 KB
    __hip_bfloat16* g = (__hip_bfloat16*)(ws + off);    off += (size_t)N_NODES * DIM * 2;      // 4 MB

    const int P0_THREADS = N_NODES / 4 + DIM * DIM / 8;  // 2048 + 8192 = 10240
    p0_prep<<<(P0_THREADS + 255) / 256, 256, 0, stream>>>(W, Wb, lens);
    k1_scatter<<<512, 256, 0, stream>>>(ei, list, lens, E);
    k2_gemm_dedup<<<1024, 256, 0, stream>>>(x, (const short*)Wb, g, list, lens, dinv);
    k3_aggregate<<<N_NODES, 128, 0, stream>>>(list, lens, dinv, (const uint4*)g, out);
}